// Round 1
// 1476.731 us; speedup vs baseline: 1.8026x; 1.8026x over previous
//
#include <hip/hip_runtime.h>
#include <hip/hip_bf16.h>

// Problem constants (B, N, C fixed by reference)
#define BB 8
#define NN 2048
#define CC 256
#define GG 64        // C / NGRP groups of 4 channels
#define QQ 8

typedef unsigned short u16;
typedef __attribute__((ext_vector_type(8))) short bf16x8;   // 8 bf16 (4 VGPRs)
typedef __attribute__((ext_vector_type(4))) float f32x4;    // MFMA accumulator

static __device__ __forceinline__ float b2f(u16 u) {
  union { unsigned int i; float f; } cv; cv.i = ((unsigned int)u) << 16; return cv.f;
}
static __device__ __forceinline__ u16 f2b(float f) {
  union { __hip_bfloat16 h; u16 u; } cv; cv.h = __float2bfloat16(f); return cv.u;
}
// dtype-flexible scalar load: flag ? float32 : bf16
static __device__ __forceinline__ float ldin(const void* p, size_t i, bool f32) {
  return f32 ? ((const float*)p)[i] : b2f(((const u16*)p)[i]);
}
// async global->LDS, 16B per lane; LDS dest = wave-uniform base + lane*16
static __device__ __forceinline__ void gload16(const void* g, void* l) {
  __builtin_amdgcn_global_load_lds(
      (const __attribute__((address_space(1))) void*)g,
      (__attribute__((address_space(3))) void*)l, 16, 0, 0);
}

// ---------------------------------------------------------------------------
// dtype detection (bf16 vs f32 inputs)
// ---------------------------------------------------------------------------
__global__ __launch_bounds__(256) void detect_kernel(const u16* __restrict__ sc,
                                                     int* __restrict__ flag)
{
  __shared__ int sh;
  if (threadIdx.x == 0) sh = 0;
  __syncthreads();
  int cnt = 0;
  for (int i = threadIdx.x; i < 2048; i += 256) {
    u16 w = sc[2 * i];
    int e = (w >> 7) & 0xFF;
    if (e >= 100 && e <= 130) cnt++;
  }
  atomicAdd(&sh, cnt);
  __syncthreads();
  if (threadIdx.x == 0) *flag = (sh < 1024) ? 1 : 0;   // 1 => float32 inputs
}

// ---------------------------------------------------------------------------
// K[bl,i,j] = 0.5*(sc[b,i,j]+sc[b,j,i]) * sigmoid(dot(U[i],U[j]))
// stored as bf16 hi/lo split (Khi + Klo == K to ~2^-17 rel)
// ---------------------------------------------------------------------------
__global__ __launch_bounds__(256) void build_k_kernel(
    const void* __restrict__ sc, const void* __restrict__ U,
    u16* __restrict__ Khi, u16* __restrict__ Klo,
    const int* __restrict__ flagp, int grp)
{
  const bool f32 = (*flagp != 0);
  const int bl = blockIdx.z;            // 0..3
  const int b  = grp * 4 + bl;
  const int i0 = blockIdx.y * 32;
  const int j0 = blockIdx.x * 32;
  const int tx = threadIdx.x;   // 0..31
  const int ty = threadIdx.y;   // 0..7
  const int t  = ty * 32 + tx;

  __shared__ float Ui[32][17];
  __shared__ float Uj[32][17];
  __shared__ float st[32][33];

  for (int s = t; s < 512; s += 256) {
    int rr = s >> 4, kk = s & 15;
    Ui[rr][kk] = ldin(U, (size_t)(i0 + rr) * 16 + kk, f32);
    Uj[rr][kk] = ldin(U, (size_t)(j0 + rr) * 16 + kk, f32);
  }
  const size_t scb = (size_t)b * NN * NN;
  for (int jj = ty; jj < 32; jj += 8)
    st[jj][tx] = ldin(sc, scb + (size_t)(j0 + jj) * NN + i0 + tx, f32);
  __syncthreads();

  const size_t kfb = (size_t)bl * NN * NN;
  for (int ii = ty; ii < 32; ii += 8) {
    float dot = 0.f;
    #pragma unroll
    for (int k = 0; k < 16; k++) dot += Ui[ii][k] * Uj[tx][k];
    float A = 1.0f / (1.0f + expf(-dot));
    float d = ldin(sc, scb + (size_t)(i0 + ii) * NN + j0 + tx, f32);
    float kv = 0.5f * (d + st[tx][ii]) * A;
    u16 h = f2b(kv);
    size_t oidx = kfb + (size_t)(i0 + ii) * NN + j0 + tx;
    Khi[oidx] = h;
    Klo[oidx] = f2b(kv - b2f(h));
  }
}

// ---------------------------------------------------------------------------
// GroupNorm stats over y[b, 4g:4g+4, :]  (8192 elems per (b,g))
// ---------------------------------------------------------------------------
__global__ __launch_bounds__(256) void gn_stats_kernel(
    const void* __restrict__ y, float* __restrict__ murs,
    const int* __restrict__ flagp)
{
  const bool f32 = (*flagp != 0);
  const int bg = blockIdx.x;                    // b*64 + g
  float s = 0.f, ss = 0.f;
  if (f32) {
    const float* base = (const float*)y + (size_t)bg * 4 * NN;
    for (int i = threadIdx.x; i < 2048; i += 256) {
      float4 v = *(const float4*)(base + (size_t)i * 4);
      s  += v.x + v.y + v.z + v.w;
      ss += v.x*v.x + v.y*v.y + v.z*v.z + v.w*v.w;
    }
  } else {
    const u16* base = (const u16*)y + (size_t)bg * 4 * NN;
    for (int i = threadIdx.x; i < 2048; i += 256) {
      ushort4 v = *(const ushort4*)(base + (size_t)i * 4);
      float f0 = b2f(v.x), f1 = b2f(v.y), f2 = b2f(v.z), f3 = b2f(v.w);
      s  += f0 + f1 + f2 + f3;
      ss += f0*f0 + f1*f1 + f2*f2 + f3*f3;
    }
  }
  #pragma unroll
  for (int off = 32; off > 0; off >>= 1) {
    s  += __shfl_down(s, off, 64);
    ss += __shfl_down(ss, off, 64);
  }
  __shared__ float sh[8];
  const int w = threadIdx.x >> 6, ln = threadIdx.x & 63;
  if (ln == 0) { sh[w * 2] = s; sh[w * 2 + 1] = ss; }
  __syncthreads();
  if (threadIdx.x == 0) {
    float S  = sh[0] + sh[2] + sh[4] + sh[6];
    float SS = sh[1] + sh[3] + sh[5] + sh[7];
    float mu  = S / 8192.0f;
    float var = SS / 8192.0f - mu * mu;
    murs[bg * 2]     = mu;
    murs[bg * 2 + 1] = 1.0f / sqrtf(fmaxf(var, 0.f) + 1e-5f);
  }
}

// ---------------------------------------------------------------------------
// y_t[b,n,c] = sphere( GN(y)[b,c,n] * w + bias ) -> f32 [b][n][c]
// ---------------------------------------------------------------------------
__global__ __launch_bounds__(256) void y_tf_kernel(
    const void* __restrict__ y, const float* __restrict__ murs,
    const void* __restrict__ gw, const void* __restrict__ gb,
    float* __restrict__ yt, const int* __restrict__ flagp)
{
  const bool f32 = (*flagp != 0);
  const int b = blockIdx.y;
  const int n = blockIdx.x * 64 + threadIdx.x;
  for (int g = threadIdx.y; g < GG; g += 4) {
    float mu = murs[(b * GG + g) * 2];
    float rs = murs[(b * GG + g) * 2 + 1];
    float v[4];
    #pragma unroll
    for (int k = 0; k < 4; k++) {
      int c = 4 * g + k;
      float val = (ldin(y, ((size_t)b * CC + c) * NN + n, f32) - mu) * rs;
      v[k] = val * ldin(gw, c, f32) + ldin(gb, c, f32);
    }
    float n2 = v[0]*v[0] + v[1]*v[1] + v[2]*v[2] + v[3]*v[3];
    float scl = 1.0f / sqrtf(fmaxf(n2, 1e-6f));
    float4 o; o.x = v[0]*scl; o.y = v[1]*scl; o.z = v[2]*scl; o.w = v[3]*scl;
    *(float4*)(yt + ((size_t)b * NN + n) * CC + 4 * g) = o;
  }
}

// ---------------------------------------------------------------------------
// x init: sphere-normalize x -> bf16 hi/lo transposed state xT[b][c][n]
// (hi+lo carries the f32 state to ~2^-18; feeds MFMA B operand k-contiguous)
// ---------------------------------------------------------------------------
__global__ __launch_bounds__(256) void x_init_kernel(
    const void* __restrict__ x, u16* __restrict__ xTh, u16* __restrict__ xTl,
    const int* __restrict__ flagp)
{
  const bool f32 = (*flagp != 0);
  const int b = blockIdx.y;
  const int n = blockIdx.x * 64 + threadIdx.x;
  for (int g = threadIdx.y; g < GG; g += 4) {
    size_t idx = ((size_t)b * NN + n) * CC + 4 * g;
    float v[4];
    if (f32) {
      float4 u4 = *(const float4*)((const float*)x + idx);
      v[0] = u4.x; v[1] = u4.y; v[2] = u4.z; v[3] = u4.w;
    } else {
      ushort4 u = *(const ushort4*)((const u16*)x + idx);
      v[0] = b2f(u.x); v[1] = b2f(u.y); v[2] = b2f(u.z); v[3] = b2f(u.w);
    }
    float n2 = v[0]*v[0] + v[1]*v[1] + v[2]*v[2] + v[3]*v[3];
    float scl = 1.0f / sqrtf(fmaxf(n2, 1e-6f));
    size_t xb = ((size_t)b * CC + 4 * g) * NN + n;
    #pragma unroll
    for (int k = 0; k < 4; k++) {
      float xv = v[k] * scl;
      u16 h = f2b(xv);
      xTh[xb + (size_t)k * NN] = h;
      xTl[xb + (size_t)k * NN] = f2b(xv - b2f(h));
    }
  }
}

// ---------------------------------------------------------------------------
// bf16x3 MFMA GEMM: coup[bl,n,c] = sum_m K[bl,n,m] * x[b,m,c]
//   K ~ Khi+Klo (bf16), x ~ xTh+xTl (bf16, stored [b][c][m]).
//   3 MFMAs per fragment pair: Ah*Bh + Ah*Bl + Al*Bh  (f32-grade precision).
// Tile: BM=128, BN=64, BK=64; 256 threads = 4 waves, wave tile 64x32.
// Staging: global_load_lds width=16, double-buffered, 2-phase pipeline.
// LDS XOR chunk-swizzle (involution, applied on global src AND ds_read addr)
// kills the stride-128B bank conflict (rule #21 / T2).
// Grid: (256/64, 2048/128, 4) = (4,16,4) = 256 blocks, 1/CU.
// ---------------------------------------------------------------------------
__global__ __launch_bounds__(256) void gemm_mfma_kernel(
    const u16* __restrict__ Khi, const u16* __restrict__ Klo,
    const u16* __restrict__ xTh, const u16* __restrict__ xTl,
    float* __restrict__ coup, int grp)
{
  const int bl = blockIdx.z;
  const int b  = grp * 4 + bl;
  const int m0 = blockIdx.y * 128;
  const int c0 = blockIdx.x * 64;

  // per buffer: Ah[128][64]bf16 @0 (16KB), Al @16384, Bh[64][64] @32768 (8KB), Bl @40960
  __shared__ char lds[2][49152];

  const int t    = threadIdx.x;
  const int lane = t & 63;
  const int wid  = t >> 6;
  const int wr   = wid >> 1;    // wave row 0..1 (M)
  const int wc   = wid & 1;     // wave col 0..1 (N)

  const u16* Ah = Khi + (size_t)bl * NN * NN;
  const u16* Al = Klo + (size_t)bl * NN * NN;
  const u16* Bh = xTh + (size_t)b * CC * NN;
  const u16* Bl = xTl + (size_t)b * CC * NN;

  // staging geometry: thread t owns 16B chunk cid = i*256+t of each region.
  // row = cid>>3, logical chunk = cid&7; fetch source chunk = logical^(row&7)
  // so linear LDS dest holds the swizzled layout the reader expects.
  const int tr   = t >> 3;                       // 0..31
  const int phys = (t & 7) ^ (tr & 7);
  const size_t aoff = (size_t)(m0 + tr) * NN + phys * 8;
  const size_t boff = (size_t)(c0 + tr) * NN + phys * 8;
  const int dst = wid * 1024;                    // + lane*16 implicit in HW

  f32x4 acc[4][2];
  const f32x4 zero4 = {0.f, 0.f, 0.f, 0.f};
  #pragma unroll
  for (int i = 0; i < 4; i++)
    #pragma unroll
    for (int j = 0; j < 2; j++) acc[i][j] = zero4;

  auto stage = [&](int bufi, int k0) {
    char* base = &lds[bufi][0];
    #pragma unroll
    for (int i = 0; i < 4; i++) {                // A hi/lo: 16KB each
      gload16(Ah + aoff + (size_t)i * (32 * NN) + k0, base + i * 4096 + dst);
      gload16(Al + aoff + (size_t)i * (32 * NN) + k0, base + 16384 + i * 4096 + dst);
    }
    #pragma unroll
    for (int i = 0; i < 2; i++) {                // B hi/lo: 8KB each
      gload16(Bh + boff + (size_t)i * (32 * NN) + k0, base + 32768 + i * 4096 + dst);
      gload16(Bl + boff + (size_t)i * (32 * NN) + k0, base + 40960 + i * 4096 + dst);
    }
  };

  const int l15 = lane & 15;
  const int lk  = lane >> 4;     // 0..3
  const int lx  = lane & 7;      // == row&7 for all fragment rows

  auto compute = [&](int bufi) {
    const char* base = &lds[bufi][0];
    #pragma unroll
    for (int ks = 0; ks < 2; ks++) {             // two K=32 MFMA steps per tile
      const int cl = ks * 4 + lk;                // logical 16B chunk (k/8)
      const int xo = (cl ^ lx) << 4;             // swizzled byte offset in row
      bf16x8 fah[4], fal[4], fbh[2], fbl[2];
      #pragma unroll
      for (int fr = 0; fr < 4; fr++) {
        int off = (wr * 64 + fr * 16 + l15) * 128 + xo;
        fah[fr] = *(const bf16x8*)(base + off);
        fal[fr] = *(const bf16x8*)(base + 16384 + off);
      }
      #pragma unroll
      for (int fc = 0; fc < 2; fc++) {
        int off = (wc * 32 + fc * 16 + l15) * 128 + xo;
        fbh[fc] = *(const bf16x8*)(base + 32768 + off);
        fbl[fc] = *(const bf16x8*)(base + 40960 + off);
      }
      #pragma unroll
      for (int fr = 0; fr < 4; fr++)
        #pragma unroll
        for (int fc = 0; fc < 2; fc++) {
          acc[fr][fc] = __builtin_amdgcn_mfma_f32_16x16x32_bf16(
              fah[fr], fbh[fc], acc[fr][fc], 0, 0, 0);
          acc[fr][fc] = __builtin_amdgcn_mfma_f32_16x16x32_bf16(
              fah[fr], fbl[fc], acc[fr][fc], 0, 0, 0);
          acc[fr][fc] = __builtin_amdgcn_mfma_f32_16x16x32_bf16(
              fal[fr], fbh[fc], acc[fr][fc], 0, 0, 0);
        }
    }
  };

  // 2-phase double-buffered pipeline; __syncthreads() drains vmcnt(0) so the
  // freshly staged buffer is visible (compiler emits the waitcnt before barrier)
  stage(0, 0);
  __syncthreads();
  int buf = 0;
  for (int kt = 0; kt < NN / 64; kt++) {
    if (kt + 1 < NN / 64) stage(buf ^ 1, (kt + 1) * 64);
    compute(buf);
    __syncthreads();
    buf ^= 1;
  }

  // epilogue: C/D layout col=lane&15, row=(lane>>4)*4+reg  [m89/m91]
  #pragma unroll
  for (int fr = 0; fr < 4; fr++) {
    const int rbase = m0 + wr * 64 + fr * 16 + lk * 4;
    #pragma unroll
    for (int fc = 0; fc < 2; fc++) {
      const int c = c0 + wc * 32 + fc * 16 + l15;
      #pragma unroll
      for (int r = 0; r < 4; r++)
        coup[((size_t)bl * NN + rbase + r) * CC + c] = acc[fr][fc][r];
    }
  }
}

// ---------------------------------------------------------------------------
// One Kuramoto step (pointwise): force, tangent projection, omega, renorm.
// State lives in xTh/xTl ([b][c][n] bf16 hi/lo); writes output + next state.
// ---------------------------------------------------------------------------
__global__ __launch_bounds__(256) void step_kernel(
    u16* __restrict__ xTh, u16* __restrict__ xTl,
    const float* __restrict__ coup, const float* __restrict__ yt,
    const void* __restrict__ omega, const void* __restrict__ gamma,
    void* __restrict__ outbase, size_t qoff,
    const int* __restrict__ flagp, int grp)
{
  const bool f32 = (*flagp != 0);
  const int bl = blockIdx.y;
  const int b  = grp * 4 + bl;
  const int n  = blockIdx.x * 64 + threadIdx.x;
  const float gm = ldin(gamma, 0, f32);
  for (int g = threadIdx.y; g < GG; g += 4) {
    size_t cidx = ((size_t)bl * NN + n) * CC + 4 * g;    // coup: 4-batch buffer
    size_t yidx = ((size_t)b  * NN + n) * CC + 4 * g;    // yt/out: 8-batch
    size_t xb   = ((size_t)b * CC + 4 * g) * NN + n;     // xT: [b][c][n]
    float4 cp4 = *(const float4*)(coup + cidx);
    float4 yv4 = *(const float4*)(yt + yidx);
    float xc[4];
    #pragma unroll
    for (int k = 0; k < 4; k++)
      xc[k] = b2f(xTh[xb + (size_t)k * NN]) + b2f(xTl[xb + (size_t)k * NN]);
    float f[4] = { cp4.x + yv4.x, cp4.y + yv4.y, cp4.z + yv4.z, cp4.w + yv4.w };
    float sim = xc[0]*f[0] + xc[1]*f[1] + xc[2]*f[2] + xc[3]*f[3];
    float om0 = fabsf(ldin(omega, 2 * g, f32));
    float om1 = fabsf(ldin(omega, 2 * g + 1, f32));
    float d0 =  om0 * xc[1] + (f[0] - sim * xc[0]);
    float d1 = -om0 * xc[0] + (f[1] - sim * xc[1]);
    float d2 =  om1 * xc[3] + (f[2] - sim * xc[2]);
    float d3 = -om1 * xc[2] + (f[3] - sim * xc[3]);
    float v[4] = { xc[0] + gm * d0, xc[1] + gm * d1, xc[2] + gm * d2, xc[3] + gm * d3 };
    float n2 = v[0]*v[0] + v[1]*v[1] + v[2]*v[2] + v[3]*v[3];
    float scl = 1.0f / sqrtf(fmaxf(n2, 1e-6f));
    float xn[4] = { v[0]*scl, v[1]*scl, v[2]*scl, v[3]*scl };
    #pragma unroll
    for (int k = 0; k < 4; k++) {
      u16 h = f2b(xn[k]);
      xTh[xb + (size_t)k * NN] = h;
      xTl[xb + (size_t)k * NN] = f2b(xn[k] - b2f(h));
    }
    if (f32) {
      float4 o; o.x = xn[0]; o.y = xn[1]; o.z = xn[2]; o.w = xn[3];
      *(float4*)((float*)outbase + qoff + yidx) = o;
    } else {
      ushort4 ob;
      ob.x = f2b(xn[0]); ob.y = f2b(xn[1]); ob.z = f2b(xn[2]); ob.w = f2b(xn[3]);
      *(ushort4*)((u16*)outbase + qoff + yidx) = ob;
    }
  }
}

// ---------------------------------------------------------------------------
extern "C" void kernel_launch(void* const* d_in, const int* in_sizes, int n_in,
                              void* d_out, int out_size, void* d_ws, size_t ws_size,
                              hipStream_t stream) {
  const void* x     = d_in[0];
  const void* y     = d_in[1];
  const void* sc    = d_in[2];
  const void* U     = d_in[3];
  const void* omega = d_in[4];
  const void* gw    = d_in[5];
  const void* gb    = d_in[6];
  const void* gamma = d_in[7];
  // d_in[8] = Q (int32) — fixed at 8 by the problem setup.
  char* ws = (char*)d_ws;

  // Workspace layout (~109.1 MB, under the 125.8 MB previously exercised)
  const size_t BNC = (size_t)BB * NN * CC;               // 4,194,304
  u16*   Khi  = (u16*)(ws);                              // 33,554,432 B
  u16*   Klo  = (u16*)(ws + 33554432);                   // 33,554,432 B
  float* yt   = (float*)(ws + 67108864);                 // 16,777,216 B
  u16*   xTh  = (u16*)(ws + 83886080);                   //  8,388,608 B
  u16*   xTl  = (u16*)(ws + 92274688);                   //  8,388,608 B
  float* coup = (float*)(ws + 100663296);                //  8,388,608 B (4 batches)
  float* murs = (float*)(ws + 109051904);                //  4 KB
  int*   flag = (int*)  (ws + 109056000);                //  4 B

  detect_kernel<<<dim3(1), dim3(256), 0, stream>>>((const u16*)sc, flag);
  gn_stats_kernel<<<dim3(512), dim3(256), 0, stream>>>(y, murs, flag);
  y_tf_kernel<<<dim3(32, 8), dim3(64, 4), 0, stream>>>(y, murs, gw, gb, yt, flag);
  x_init_kernel<<<dim3(32, 8), dim3(64, 4), 0, stream>>>(x, xTh, xTl, flag);

  for (int grp = 0; grp < 2; grp++) {
    build_k_kernel<<<dim3(64, 64, 4), dim3(32, 8), 0, stream>>>(
        sc, U, Khi, Klo, flag, grp);
    for (int q = 0; q < QQ; q++) {
      gemm_mfma_kernel<<<dim3(4, 16, 4), dim3(256), 0, stream>>>(
          Khi, Klo, xTh, xTl, coup, grp);
      step_kernel<<<dim3(32, 4), dim3(64, 4), 0, stream>>>(
          xTh, xTl, coup, yt, omega, gamma, d_out, (size_t)q * BNC, flag, grp);
    }
  }
}

// Round 2
// 1216.514 us; speedup vs baseline: 2.1882x; 1.2139x over previous
//
#include <hip/hip_runtime.h>
#include <hip/hip_bf16.h>

// Problem constants (B, N, C fixed by reference)
#define BB 8
#define NN 2048
#define CC 256
#define GG 64        // C / NGRP groups of 4 channels
#define QQ 8

typedef unsigned short u16;
typedef __attribute__((ext_vector_type(8))) short bf16x8;   // 8 bf16 (4 VGPRs)
typedef __attribute__((ext_vector_type(4))) float f32x4;    // MFMA accumulator

static __device__ __forceinline__ float b2f(u16 u) {
  union { unsigned int i; float f; } cv; cv.i = ((unsigned int)u) << 16; return cv.f;
}
static __device__ __forceinline__ u16 f2b(float f) {
  union { __hip_bfloat16 h; u16 u; } cv; cv.h = __float2bfloat16(f); return cv.u;
}
// dtype-flexible scalar load: flag ? float32 : bf16
static __device__ __forceinline__ float ldin(const void* p, size_t i, bool f32) {
  return f32 ? ((const float*)p)[i] : b2f(((const u16*)p)[i]);
}
// async global->LDS, 16B per lane; LDS dest = wave-uniform base + lane*16
static __device__ __forceinline__ void gload16(const void* g, void* l) {
  __builtin_amdgcn_global_load_lds(
      (const __attribute__((address_space(1))) void*)g,
      (__attribute__((address_space(3))) void*)l, 16, 0, 0);
}

// ---------------------------------------------------------------------------
// dtype detection (bf16 vs f32 inputs)
// ---------------------------------------------------------------------------
__global__ __launch_bounds__(256) void detect_kernel(const u16* __restrict__ sc,
                                                     int* __restrict__ flag)
{
  __shared__ int sh;
  if (threadIdx.x == 0) sh = 0;
  __syncthreads();
  int cnt = 0;
  for (int i = threadIdx.x; i < 2048; i += 256) {
    u16 w = sc[2 * i];
    int e = (w >> 7) & 0xFF;
    if (e >= 100 && e <= 130) cnt++;
  }
  atomicAdd(&sh, cnt);
  __syncthreads();
  if (threadIdx.x == 0) *flag = (sh < 1024) ? 1 : 0;   // 1 => float32 inputs
}

// ---------------------------------------------------------------------------
// K[bl,i,j] = 0.5*(sc[b,i,j]+sc[b,j,i]) * sigmoid(dot(U[i],U[j]))
// Symmetric-pair version: one block per (i0<=j0) tile pair; A=sigmoid(UU^T)
// computed ONCE (it is batch-independent and symmetric), then 4 batches
// write both the (i,j) and (j,i) K-tiles as bf16 hi/lo.
// Grid (64,64); lower-triangle blocks exit immediately.
// ---------------------------------------------------------------------------
__global__ __launch_bounds__(256) void build_k_kernel(
    const void* __restrict__ sc, const void* __restrict__ U,
    u16* __restrict__ Khi, u16* __restrict__ Klo,
    const int* __restrict__ flagp, int grp)
{
  const int i0 = blockIdx.y * 32;
  const int j0 = blockIdx.x * 32;
  if (j0 < i0) return;
  const bool f32 = (*flagp != 0);
  const int tx = threadIdx.x;   // 0..31
  const int ty = threadIdx.y;   // 0..7
  const int t  = ty * 32 + tx;

  __shared__ float Ui[32][17];
  __shared__ float Uj[32][17];
  __shared__ float As[32][33];   // As[a][b] = sigmoid(dot(U[i0+a], U[j0+b]))
  __shared__ float t1[32][33];   // t1[a][b] = sc[b, i0+a, j0+b]
  __shared__ float t2[32][33];   // t2[a][b] = sc[b, j0+a, i0+b]

  for (int s = t; s < 512; s += 256) {
    int rr = s >> 4, kk = s & 15;
    Ui[rr][kk] = ldin(U, (size_t)(i0 + rr) * 16 + kk, f32);
    Uj[rr][kk] = ldin(U, (size_t)(j0 + rr) * 16 + kk, f32);
  }
  __syncthreads();
  for (int ii = ty; ii < 32; ii += 8) {
    float dot = 0.f;
    #pragma unroll
    for (int k = 0; k < 16; k++) dot += Ui[ii][k] * Uj[tx][k];
    As[ii][tx] = 1.0f / (1.0f + expf(-dot));
  }

  for (int bl = 0; bl < 4; bl++) {
    const int b = grp * 4 + bl;
    const size_t scb = (size_t)b * NN * NN;
    __syncthreads();                       // protect t1/t2 (and As on bl=0)
    for (int ii = ty; ii < 32; ii += 8) {
      t1[ii][tx] = ldin(sc, scb + (size_t)(i0 + ii) * NN + j0 + tx, f32);
      t2[ii][tx] = ldin(sc, scb + (size_t)(j0 + ii) * NN + i0 + tx, f32);
    }
    __syncthreads();
    const size_t kfb = (size_t)bl * NN * NN;
    for (int ii = ty; ii < 32; ii += 8) {
      // tile (i0, j0): row i0+ii, col j0+tx
      float kv = 0.5f * (t1[ii][tx] + t2[tx][ii]) * As[ii][tx];
      u16 h = f2b(kv);
      size_t o = kfb + (size_t)(i0 + ii) * NN + j0 + tx;
      Khi[o] = h;
      Klo[o] = f2b(kv - b2f(h));
      if (i0 != j0) {
        // tile (j0, i0): row j0+ii, col i0+tx; A symmetric -> As[tx][ii]
        float kv2 = 0.5f * (t2[ii][tx] + t1[tx][ii]) * As[tx][ii];
        u16 h2 = f2b(kv2);
        size_t o2 = kfb + (size_t)(j0 + ii) * NN + i0 + tx;
        Khi[o2] = h2;
        Klo[o2] = f2b(kv2 - b2f(h2));
      }
    }
  }
}

// ---------------------------------------------------------------------------
// GroupNorm stats over y[b, 4g:4g+4, :]  (8192 elems per (b,g))
// ---------------------------------------------------------------------------
__global__ __launch_bounds__(256) void gn_stats_kernel(
    const void* __restrict__ y, float* __restrict__ murs,
    const int* __restrict__ flagp)
{
  const bool f32 = (*flagp != 0);
  const int bg = blockIdx.x;                    // b*64 + g
  float s = 0.f, ss = 0.f;
  if (f32) {
    const float* base = (const float*)y + (size_t)bg * 4 * NN;
    for (int i = threadIdx.x; i < 2048; i += 256) {
      float4 v = *(const float4*)(base + (size_t)i * 4);
      s  += v.x + v.y + v.z + v.w;
      ss += v.x*v.x + v.y*v.y + v.z*v.z + v.w*v.w;
    }
  } else {
    const u16* base = (const u16*)y + (size_t)bg * 4 * NN;
    for (int i = threadIdx.x; i < 2048; i += 256) {
      ushort4 v = *(const ushort4*)(base + (size_t)i * 4);
      float f0 = b2f(v.x), f1 = b2f(v.y), f2 = b2f(v.z), f3 = b2f(v.w);
      s  += f0 + f1 + f2 + f3;
      ss += f0*f0 + f1*f1 + f2*f2 + f3*f3;
    }
  }
  #pragma unroll
  for (int off = 32; off > 0; off >>= 1) {
    s  += __shfl_down(s, off, 64);
    ss += __shfl_down(ss, off, 64);
  }
  __shared__ float sh[8];
  const int w = threadIdx.x >> 6, ln = threadIdx.x & 63;
  if (ln == 0) { sh[w * 2] = s; sh[w * 2 + 1] = ss; }
  __syncthreads();
  if (threadIdx.x == 0) {
    float S  = sh[0] + sh[2] + sh[4] + sh[6];
    float SS = sh[1] + sh[3] + sh[5] + sh[7];
    float mu  = S / 8192.0f;
    float var = SS / 8192.0f - mu * mu;
    murs[bg * 2]     = mu;
    murs[bg * 2 + 1] = 1.0f / sqrtf(fmaxf(var, 0.f) + 1e-5f);
  }
}

// ---------------------------------------------------------------------------
// y_t[b,n,c] = sphere( GN(y)[b,c,n] * w + bias ) -> f32 [b][n][c]
// ---------------------------------------------------------------------------
__global__ __launch_bounds__(256) void y_tf_kernel(
    const void* __restrict__ y, const float* __restrict__ murs,
    const void* __restrict__ gw, const void* __restrict__ gb,
    float* __restrict__ yt, const int* __restrict__ flagp)
{
  const bool f32 = (*flagp != 0);
  const int b = blockIdx.y;
  const int n = blockIdx.x * 64 + threadIdx.x;
  for (int g = threadIdx.y; g < GG; g += 4) {
    float mu = murs[(b * GG + g) * 2];
    float rs = murs[(b * GG + g) * 2 + 1];
    float v[4];
    #pragma unroll
    for (int k = 0; k < 4; k++) {
      int c = 4 * g + k;
      float val = (ldin(y, ((size_t)b * CC + c) * NN + n, f32) - mu) * rs;
      v[k] = val * ldin(gw, c, f32) + ldin(gb, c, f32);
    }
    float n2 = v[0]*v[0] + v[1]*v[1] + v[2]*v[2] + v[3]*v[3];
    float scl = 1.0f / sqrtf(fmaxf(n2, 1e-6f));
    float4 o; o.x = v[0]*scl; o.y = v[1]*scl; o.z = v[2]*scl; o.w = v[3]*scl;
    *(float4*)(yt + ((size_t)b * NN + n) * CC + 4 * g) = o;
  }
}

// ---------------------------------------------------------------------------
// x init: sphere-normalize x -> bf16 hi/lo transposed state xT[b][c][n]
// ---------------------------------------------------------------------------
__global__ __launch_bounds__(256) void x_init_kernel(
    const void* __restrict__ x, u16* __restrict__ xTh, u16* __restrict__ xTl,
    const int* __restrict__ flagp)
{
  const bool f32 = (*flagp != 0);
  const int b = blockIdx.y;
  const int n = blockIdx.x * 64 + threadIdx.x;
  for (int g = threadIdx.y; g < GG; g += 4) {
    size_t idx = ((size_t)b * NN + n) * CC + 4 * g;
    float v[4];
    if (f32) {
      float4 u4 = *(const float4*)((const float*)x + idx);
      v[0] = u4.x; v[1] = u4.y; v[2] = u4.z; v[3] = u4.w;
    } else {
      ushort4 u = *(const ushort4*)((const u16*)x + idx);
      v[0] = b2f(u.x); v[1] = b2f(u.y); v[2] = b2f(u.z); v[3] = b2f(u.w);
    }
    float n2 = v[0]*v[0] + v[1]*v[1] + v[2]*v[2] + v[3]*v[3];
    float scl = 1.0f / sqrtf(fmaxf(n2, 1e-6f));
    size_t xb = ((size_t)b * CC + 4 * g) * NN + n;
    #pragma unroll
    for (int k = 0; k < 4; k++) {
      float xv = v[k] * scl;
      u16 h = f2b(xv);
      xTh[xb + (size_t)k * NN] = h;
      xTl[xb + (size_t)k * NN] = f2b(xv - b2f(h));
    }
  }
}

// ---------------------------------------------------------------------------
// bf16x3 MFMA GEMM: coup[bl,n,c] = sum_m K[bl,n,m] * x[b,m,c]
// Tile: BM=64, BN=64, BK=64; 256 threads = 4 waves, wave tile 32x32 (2x2
// 16x16 frags). LDS 2 x 32KB double buffer -> 2 blocks/CU, 2 waves/SIMD:
// one block computes while the other drains its staging (the m97 mechanism
// that the previous 1-block/CU 128x64 version was missing).
// Staging: global_load_lds width=16, XOR chunk-swizzle (involution on both
// the global source and the ds_read address; linear LDS dest — rule #21).
// Grid: (256/64, 2048/64, 4) = (4,32,4) = 512 blocks.
// ---------------------------------------------------------------------------
__global__ __launch_bounds__(256, 2) void gemm_mfma_kernel(
    const u16* __restrict__ Khi, const u16* __restrict__ Klo,
    const u16* __restrict__ xTh, const u16* __restrict__ xTl,
    float* __restrict__ coup, int grp)
{
  const int bl = blockIdx.z;
  const int b  = grp * 4 + bl;
  const int m0 = blockIdx.y * 64;
  const int c0 = blockIdx.x * 64;

  // per buffer: Ah[64][64]bf16 @0 (8KB), Al @8192, Bh @16384, Bl @24576
  __shared__ char lds[2][32768];

  const int t    = threadIdx.x;
  const int lane = t & 63;
  const int wid  = t >> 6;
  const int wr   = wid >> 1;    // wave row 0..1 (M)
  const int wc   = wid & 1;     // wave col 0..1 (N)

  const u16* Ah = Khi + (size_t)bl * NN * NN;
  const u16* Al = Klo + (size_t)bl * NN * NN;
  const u16* Bh = xTh + (size_t)b * CC * NN;
  const u16* Bl = xTl + (size_t)b * CC * NN;

  // staging geometry: region = 64 rows x 128B. chunk c = i*256 + t,
  // row = c>>3 = i*32 + (t>>3), in-row chunk = t&7; source chunk =
  // (t&7) ^ (row&7)  (row&7 identical for i=0,1 since 32 ≡ 0 mod 8).
  const int tr   = t >> 3;                       // 0..31
  const int phys = (t & 7) ^ (tr & 7);
  const size_t aoff = (size_t)(m0 + tr) * NN + phys * 8;
  const size_t boff = (size_t)(c0 + tr) * NN + phys * 8;
  const int dst = wid * 1024;                    // + lane*16 implicit in HW

  f32x4 acc[2][2];
  const f32x4 zero4 = {0.f, 0.f, 0.f, 0.f};
  #pragma unroll
  for (int i = 0; i < 2; i++)
    #pragma unroll
    for (int j = 0; j < 2; j++) acc[i][j] = zero4;

  auto stage = [&](int bufi, int k0) {
    char* base = &lds[bufi][0];
    #pragma unroll
    for (int i = 0; i < 2; i++) {
      gload16(Ah + aoff + (size_t)i * (32 * NN) + k0, base +         i * 4096 + dst);
      gload16(Al + aoff + (size_t)i * (32 * NN) + k0, base +  8192 + i * 4096 + dst);
      gload16(Bh + boff + (size_t)i * (32 * NN) + k0, base + 16384 + i * 4096 + dst);
      gload16(Bl + boff + (size_t)i * (32 * NN) + k0, base + 24576 + i * 4096 + dst);
    }
  };

  const int l15 = lane & 15;
  const int lk  = lane >> 4;     // 0..3

  auto compute = [&](int bufi) {
    const char* base = &lds[bufi][0];
    #pragma unroll
    for (int ks = 0; ks < 2; ks++) {             // two K=32 MFMA steps per tile
      const int cl = ks * 4 + lk;                // logical 16B chunk (k/8)
      bf16x8 fah[2], fal[2], fbh[2], fbl[2];
      #pragma unroll
      for (int fr = 0; fr < 2; fr++) {
        int r   = wr * 32 + fr * 16 + l15;
        int off = r * 128 + ((cl ^ (r & 7)) << 4);
        fah[fr] = *(const bf16x8*)(base + off);
        fal[fr] = *(const bf16x8*)(base + 8192 + off);
      }
      #pragma unroll
      for (int fc = 0; fc < 2; fc++) {
        int r   = wc * 32 + fc * 16 + l15;
        int off = r * 128 + ((cl ^ (r & 7)) << 4);
        fbh[fc] = *(const bf16x8*)(base + 16384 + off);
        fbl[fc] = *(const bf16x8*)(base + 24576 + off);
      }
      #pragma unroll
      for (int fr = 0; fr < 2; fr++)
        #pragma unroll
        for (int fc = 0; fc < 2; fc++) {
          acc[fr][fc] = __builtin_amdgcn_mfma_f32_16x16x32_bf16(
              fah[fr], fbh[fc], acc[fr][fc], 0, 0, 0);
          acc[fr][fc] = __builtin_amdgcn_mfma_f32_16x16x32_bf16(
              fah[fr], fbl[fc], acc[fr][fc], 0, 0, 0);
          acc[fr][fc] = __builtin_amdgcn_mfma_f32_16x16x32_bf16(
              fal[fr], fbh[fc], acc[fr][fc], 0, 0, 0);
        }
    }
  };

  stage(0, 0);
  __syncthreads();
  int buf = 0;
  for (int kt = 0; kt < NN / 64; kt++) {
    if (kt + 1 < NN / 64) stage(buf ^ 1, (kt + 1) * 64);
    compute(buf);
    __syncthreads();
    buf ^= 1;
  }

  // epilogue: C/D layout col=lane&15, row=(lane>>4)*4+reg  [m89/m91]
  #pragma unroll
  for (int fr = 0; fr < 2; fr++) {
    const int rbase = m0 + wr * 32 + fr * 16 + lk * 4;
    #pragma unroll
    for (int fc = 0; fc < 2; fc++) {
      const int c = c0 + wc * 32 + fc * 16 + l15;
      #pragma unroll
      for (int r = 0; r < 4; r++)
        coup[((size_t)bl * NN + rbase + r) * CC + c] = acc[fr][fc][r];
    }
  }
}

// ---------------------------------------------------------------------------
// One Kuramoto step (pointwise): force, tangent projection, omega, renorm.
// State lives in xTh/xTl ([b][c][n] bf16 hi/lo); writes output + next state.
// Grid (32, 4, 2): z splits the group range -> 256 blocks (all CUs).
// ---------------------------------------------------------------------------
__global__ __launch_bounds__(256) void step_kernel(
    u16* __restrict__ xTh, u16* __restrict__ xTl,
    const float* __restrict__ coup, const float* __restrict__ yt,
    const void* __restrict__ omega, const void* __restrict__ gamma,
    void* __restrict__ outbase, size_t qoff,
    const int* __restrict__ flagp, int grp)
{
  const bool f32 = (*flagp != 0);
  const int bl = blockIdx.y;
  const int b  = grp * 4 + bl;
  const int n  = blockIdx.x * 64 + threadIdx.x;
  const int g0 = blockIdx.z * 32;
  const float gm = ldin(gamma, 0, f32);
  for (int g = g0 + threadIdx.y; g < g0 + 32; g += 4) {
    size_t cidx = ((size_t)bl * NN + n) * CC + 4 * g;    // coup: 4-batch buffer
    size_t yidx = ((size_t)b  * NN + n) * CC + 4 * g;    // yt/out: 8-batch
    size_t xb   = ((size_t)b * CC + 4 * g) * NN + n;     // xT: [b][c][n]
    float4 cp4 = *(const float4*)(coup + cidx);
    float4 yv4 = *(const float4*)(yt + yidx);
    float xc[4];
    #pragma unroll
    for (int k = 0; k < 4; k++)
      xc[k] = b2f(xTh[xb + (size_t)k * NN]) + b2f(xTl[xb + (size_t)k * NN]);
    float f[4] = { cp4.x + yv4.x, cp4.y + yv4.y, cp4.z + yv4.z, cp4.w + yv4.w };
    float sim = xc[0]*f[0] + xc[1]*f[1] + xc[2]*f[2] + xc[3]*f[3];
    float om0 = fabsf(ldin(omega, 2 * g, f32));
    float om1 = fabsf(ldin(omega, 2 * g + 1, f32));
    float d0 =  om0 * xc[1] + (f[0] - sim * xc[0]);
    float d1 = -om0 * xc[0] + (f[1] - sim * xc[1]);
    float d2 =  om1 * xc[3] + (f[2] - sim * xc[2]);
    float d3 = -om1 * xc[2] + (f[3] - sim * xc[3]);
    float v[4] = { xc[0] + gm * d0, xc[1] + gm * d1, xc[2] + gm * d2, xc[3] + gm * d3 };
    float n2 = v[0]*v[0] + v[1]*v[1] + v[2]*v[2] + v[3]*v[3];
    float scl = 1.0f / sqrtf(fmaxf(n2, 1e-6f));
    float xn[4] = { v[0]*scl, v[1]*scl, v[2]*scl, v[3]*scl };
    #pragma unroll
    for (int k = 0; k < 4; k++) {
      u16 h = f2b(xn[k]);
      xTh[xb + (size_t)k * NN] = h;
      xTl[xb + (size_t)k * NN] = f2b(xn[k] - b2f(h));
    }
    if (f32) {
      float4 o; o.x = xn[0]; o.y = xn[1]; o.z = xn[2]; o.w = xn[3];
      *(float4*)((float*)outbase + qoff + yidx) = o;
    } else {
      ushort4 ob;
      ob.x = f2b(xn[0]); ob.y = f2b(xn[1]); ob.z = f2b(xn[2]); ob.w = f2b(xn[3]);
      *(ushort4*)((u16*)outbase + qoff + yidx) = ob;
    }
  }
}

// ---------------------------------------------------------------------------
extern "C" void kernel_launch(void* const* d_in, const int* in_sizes, int n_in,
                              void* d_out, int out_size, void* d_ws, size_t ws_size,
                              hipStream_t stream) {
  const void* x     = d_in[0];
  const void* y     = d_in[1];
  const void* sc    = d_in[2];
  const void* U     = d_in[3];
  const void* omega = d_in[4];
  const void* gw    = d_in[5];
  const void* gb    = d_in[6];
  const void* gamma = d_in[7];
  // d_in[8] = Q (int32) — fixed at 8 by the problem setup.
  char* ws = (char*)d_ws;

  // Workspace layout (~109.1 MB, unchanged from previous round)
  const size_t BNC = (size_t)BB * NN * CC;               // 4,194,304
  u16*   Khi  = (u16*)(ws);                              // 33,554,432 B
  u16*   Klo  = (u16*)(ws + 33554432);                   // 33,554,432 B
  float* yt   = (float*)(ws + 67108864);                 // 16,777,216 B
  u16*   xTh  = (u16*)(ws + 83886080);                   //  8,388,608 B
  u16*   xTl  = (u16*)(ws + 92274688);                   //  8,388,608 B
  float* coup = (float*)(ws + 100663296);                //  8,388,608 B (4 batches)
  float* murs = (float*)(ws + 109051904);                //  4 KB
  int*   flag = (int*)  (ws + 109056000);                //  4 B

  detect_kernel<<<dim3(1), dim3(256), 0, stream>>>((const u16*)sc, flag);
  gn_stats_kernel<<<dim3(512), dim3(256), 0, stream>>>(y, murs, flag);
  y_tf_kernel<<<dim3(32, 8), dim3(64, 4), 0, stream>>>(y, murs, gw, gb, yt, flag);
  x_init_kernel<<<dim3(32, 8), dim3(64, 4), 0, stream>>>(x, xTh, xTl, flag);

  for (int grp = 0; grp < 2; grp++) {
    build_k_kernel<<<dim3(64, 64), dim3(32, 8), 0, stream>>>(
        sc, U, Khi, Klo, flag, grp);
    for (int q = 0; q < QQ; q++) {
      gemm_mfma_kernel<<<dim3(4, 32, 4), dim3(256), 0, stream>>>(
          Khi, Klo, xTh, xTl, coup, grp);
      step_kernel<<<dim3(32, 4, 2), dim3(64, 4), 0, stream>>>(
          xTh, xTl, coup, yt, omega, gamma, d_out, (size_t)q * BNC, flag, grp);
    }
  }
}

// Round 3
// 916.300 us; speedup vs baseline: 2.9051x; 1.3276x over previous
//
#include <hip/hip_runtime.h>
#include <hip/hip_bf16.h>

// Problem constants (B, N, C fixed by reference)
#define BB 8
#define NN 2048
#define CC 256
#define GG 64        // C / NGRP groups of 4 channels
#define QQ 8

typedef unsigned short u16;
typedef __attribute__((ext_vector_type(8))) short bf16x8;   // 8 bf16 (4 VGPRs)
typedef __attribute__((ext_vector_type(4))) float f32x4;    // MFMA accumulator

static __device__ __forceinline__ float b2f(u16 u) {
  union { unsigned int i; float f; } cv; cv.i = ((unsigned int)u) << 16; return cv.f;
}
static __device__ __forceinline__ u16 f2b(float f) {
  union { __hip_bfloat16 h; u16 u; } cv; cv.h = __float2bfloat16(f); return cv.u;
}
// dtype-flexible scalar load: flag ? float32 : bf16
static __device__ __forceinline__ float ldin(const void* p, size_t i, bool f32) {
  return f32 ? ((const float*)p)[i] : b2f(((const u16*)p)[i]);
}
// 4 consecutive elements as float4 (dtype-flexible)
static __device__ __forceinline__ float4 ldin4(const void* p, size_t i, bool f32) {
  if (f32) return *(const float4*)((const float*)p + i);
  ushort4 u = *(const ushort4*)((const u16*)p + i);
  return make_float4(b2f(u.x), b2f(u.y), b2f(u.z), b2f(u.w));
}
// async global->LDS, 16B per lane; LDS dest = wave-uniform base + lane*16
static __device__ __forceinline__ void gload16(const void* g, void* l) {
  __builtin_amdgcn_global_load_lds(
      (const __attribute__((address_space(1))) void*)g,
      (__attribute__((address_space(3))) void*)l, 16, 0, 0);
}

// ---------------------------------------------------------------------------
// dtype detection (bf16 vs f32 inputs)
// ---------------------------------------------------------------------------
__global__ __launch_bounds__(256) void detect_kernel(const u16* __restrict__ sc,
                                                     int* __restrict__ flag)
{
  __shared__ int sh;
  if (threadIdx.x == 0) sh = 0;
  __syncthreads();
  int cnt = 0;
  for (int i = threadIdx.x; i < 2048; i += 256) {
    u16 w = sc[2 * i];
    int e = (w >> 7) & 0xFF;
    if (e >= 100 && e <= 130) cnt++;
  }
  atomicAdd(&sh, cnt);
  __syncthreads();
  if (threadIdx.x == 0) *flag = (sh < 1024) ? 1 : 0;   // 1 => float32 inputs
}

// ---------------------------------------------------------------------------
// K[bl,i,j] = 0.5*(sc[b,i,j]+sc[b,j,i]) * sigmoid(dot(U[i],U[j]))
// Symmetric-pair version; A computed once per block; float4/ushort4 I/O.
// Grid (64,64); lower-triangle blocks exit immediately.
// ---------------------------------------------------------------------------
__global__ __launch_bounds__(256) void build_k_kernel(
    const void* __restrict__ sc, const void* __restrict__ U,
    u16* __restrict__ Khi, u16* __restrict__ Klo,
    const int* __restrict__ flagp, int grp)
{
  const int i0 = blockIdx.y * 32;
  const int j0 = blockIdx.x * 32;
  if (j0 < i0) return;
  const bool f32 = (*flagp != 0);
  const int tx = threadIdx.x;   // 0..31
  const int ty = threadIdx.y;   // 0..7
  const int t  = ty * 32 + tx;
  const int rr = t >> 3;        // row 0..31
  const int cq = t & 7;         // col quad 0..7 (cols 4cq..4cq+3)

  __shared__ float Ui[32][17];
  __shared__ float Uj[32][17];
  __shared__ float As[32][33];   // As[a][c] = sigmoid(dot(U[i0+a], U[j0+c]))
  __shared__ float t1[32][33];   // t1[a][c] = sc[b, i0+a, j0+c]
  __shared__ float t2[32][33];   // t2[a][c] = sc[b, j0+a, i0+c]

  for (int s = t; s < 512; s += 256) {
    int r2 = s >> 4, kk = s & 15;
    Ui[r2][kk] = ldin(U, (size_t)(i0 + r2) * 16 + kk, f32);
    Uj[r2][kk] = ldin(U, (size_t)(j0 + r2) * 16 + kk, f32);
  }
  __syncthreads();
  for (int ii = ty; ii < 32; ii += 8) {
    float dot = 0.f;
    #pragma unroll
    for (int k = 0; k < 16; k++) dot += Ui[ii][k] * Uj[tx][k];
    As[ii][tx] = 1.0f / (1.0f + expf(-dot));
  }

  for (int bl = 0; bl < 4; bl++) {
    const int b = grp * 4 + bl;
    const size_t scb = (size_t)b * NN * NN;
    __syncthreads();                       // protect t1/t2 (and As on bl=0)
    float4 va = ldin4(sc, scb + (size_t)(i0 + rr) * NN + j0 + 4 * cq, f32);
    float4 vb = ldin4(sc, scb + (size_t)(j0 + rr) * NN + i0 + 4 * cq, f32);
    t1[rr][4*cq+0] = va.x; t1[rr][4*cq+1] = va.y;
    t1[rr][4*cq+2] = va.z; t1[rr][4*cq+3] = va.w;
    t2[rr][4*cq+0] = vb.x; t2[rr][4*cq+1] = vb.y;
    t2[rr][4*cq+2] = vb.z; t2[rr][4*cq+3] = vb.w;
    __syncthreads();
    const size_t kfb = (size_t)bl * NN * NN;
    ushort4 h4, l4;
    #pragma unroll
    for (int k = 0; k < 4; k++) {
      int col = 4 * cq + k;
      float kv = 0.5f * (t1[rr][col] + t2[col][rr]) * As[rr][col];
      u16 h = f2b(kv);
      ((u16*)&h4)[k] = h;
      ((u16*)&l4)[k] = f2b(kv - b2f(h));
    }
    size_t o = kfb + (size_t)(i0 + rr) * NN + j0 + 4 * cq;
    *(ushort4*)(Khi + o) = h4;
    *(ushort4*)(Klo + o) = l4;
    if (i0 != j0) {
      #pragma unroll
      for (int k = 0; k < 4; k++) {
        int col = 4 * cq + k;
        float kv = 0.5f * (t2[rr][col] + t1[col][rr]) * As[col][rr];
        u16 h = f2b(kv);
        ((u16*)&h4)[k] = h;
        ((u16*)&l4)[k] = f2b(kv - b2f(h));
      }
      size_t o2 = kfb + (size_t)(j0 + rr) * NN + i0 + 4 * cq;
      *(ushort4*)(Khi + o2) = h4;
      *(ushort4*)(Klo + o2) = l4;
    }
  }
}

// ---------------------------------------------------------------------------
// GroupNorm stats over y[b, 4g:4g+4, :]  (8192 elems per (b,g))
// ---------------------------------------------------------------------------
__global__ __launch_bounds__(256) void gn_stats_kernel(
    const void* __restrict__ y, float* __restrict__ murs,
    const int* __restrict__ flagp)
{
  const bool f32 = (*flagp != 0);
  const int bg = blockIdx.x;                    // b*64 + g
  float s = 0.f, ss = 0.f;
  if (f32) {
    const float* base = (const float*)y + (size_t)bg * 4 * NN;
    for (int i = threadIdx.x; i < 2048; i += 256) {
      float4 v = *(const float4*)(base + (size_t)i * 4);
      s  += v.x + v.y + v.z + v.w;
      ss += v.x*v.x + v.y*v.y + v.z*v.z + v.w*v.w;
    }
  } else {
    const u16* base = (const u16*)y + (size_t)bg * 4 * NN;
    for (int i = threadIdx.x; i < 2048; i += 256) {
      ushort4 v = *(const ushort4*)(base + (size_t)i * 4);
      float f0 = b2f(v.x), f1 = b2f(v.y), f2 = b2f(v.z), f3 = b2f(v.w);
      s  += f0 + f1 + f2 + f3;
      ss += f0*f0 + f1*f1 + f2*f2 + f3*f3;
    }
  }
  #pragma unroll
  for (int off = 32; off > 0; off >>= 1) {
    s  += __shfl_down(s, off, 64);
    ss += __shfl_down(ss, off, 64);
  }
  __shared__ float sh[8];
  const int w = threadIdx.x >> 6, ln = threadIdx.x & 63;
  if (ln == 0) { sh[w * 2] = s; sh[w * 2 + 1] = ss; }
  __syncthreads();
  if (threadIdx.x == 0) {
    float S  = sh[0] + sh[2] + sh[4] + sh[6];
    float SS = sh[1] + sh[3] + sh[5] + sh[7];
    float mu  = S / 8192.0f;
    float var = SS / 8192.0f - mu * mu;
    murs[bg * 2]     = mu;
    murs[bg * 2 + 1] = 1.0f / sqrtf(fmaxf(var, 0.f) + 1e-5f);
  }
}

// ---------------------------------------------------------------------------
// y_t[b,n,c] = sphere( GN(y)[b,c,n] * w + bias ) -> f32 [b][n][c]
// ---------------------------------------------------------------------------
__global__ __launch_bounds__(256) void y_tf_kernel(
    const void* __restrict__ y, const float* __restrict__ murs,
    const void* __restrict__ gw, const void* __restrict__ gb,
    float* __restrict__ yt, const int* __restrict__ flagp)
{
  const bool f32 = (*flagp != 0);
  const int b = blockIdx.y;
  const int n = blockIdx.x * 64 + threadIdx.x;
  for (int g = threadIdx.y; g < GG; g += 4) {
    float mu = murs[(b * GG + g) * 2];
    float rs = murs[(b * GG + g) * 2 + 1];
    float v[4];
    #pragma unroll
    for (int k = 0; k < 4; k++) {
      int c = 4 * g + k;
      float val = (ldin(y, ((size_t)b * CC + c) * NN + n, f32) - mu) * rs;
      v[k] = val * ldin(gw, c, f32) + ldin(gb, c, f32);
    }
    float n2 = v[0]*v[0] + v[1]*v[1] + v[2]*v[2] + v[3]*v[3];
    float scl = 1.0f / sqrtf(fmaxf(n2, 1e-6f));
    float4 o; o.x = v[0]*scl; o.y = v[1]*scl; o.z = v[2]*scl; o.w = v[3]*scl;
    *(float4*)(yt + ((size_t)b * NN + n) * CC + 4 * g) = o;
  }
}

// ---------------------------------------------------------------------------
// x init: sphere-normalize x -> bf16 hi/lo transposed state xT[b][c][n]
// ---------------------------------------------------------------------------
__global__ __launch_bounds__(256) void x_init_kernel(
    const void* __restrict__ x, u16* __restrict__ xTh, u16* __restrict__ xTl,
    const int* __restrict__ flagp)
{
  const bool f32 = (*flagp != 0);
  const int b = blockIdx.y;
  const int n = blockIdx.x * 64 + threadIdx.x;
  for (int g = threadIdx.y; g < GG; g += 4) {
    size_t idx = ((size_t)b * NN + n) * CC + 4 * g;
    float v[4];
    if (f32) {
      float4 u4 = *(const float4*)((const float*)x + idx);
      v[0] = u4.x; v[1] = u4.y; v[2] = u4.z; v[3] = u4.w;
    } else {
      ushort4 u = *(const ushort4*)((const u16*)x + idx);
      v[0] = b2f(u.x); v[1] = b2f(u.y); v[2] = b2f(u.z); v[3] = b2f(u.w);
    }
    float n2 = v[0]*v[0] + v[1]*v[1] + v[2]*v[2] + v[3]*v[3];
    float scl = 1.0f / sqrtf(fmaxf(n2, 1e-6f));
    size_t xb = ((size_t)b * CC + 4 * g) * NN + n;
    #pragma unroll
    for (int k = 0; k < 4; k++) {
      float xv = v[k] * scl;
      u16 h = f2b(xv);
      xTh[xb + (size_t)k * NN] = h;
      xTl[xb + (size_t)k * NN] = f2b(xv - b2f(h));
    }
  }
}

// ---------------------------------------------------------------------------
// Fused bf16x3 MFMA GEMM + Kuramoto step.
//   coup = K.x (bf16 hi/lo x3 MFMA, f32 acc), then the pointwise step is
//   applied IN THE EPILOGUE: a 4-channel group lives in 4 adjacent lanes
//   (l15&3) of one fragment -> sim / group-norm via __shfl_xor(1/2).
// State ping-pong: reads xhc/xlc, writes xhn/xln (no intra-dispatch race
// with B-operand staging, which reads the full n-range of xhc/xlc).
// XCD-chunked swizzle: HW round-robins flat id over 8 XCDs; remap so each
// XCD owns 64 contiguous logical blocks -> A-panel (4 sharers) and B-panel
// (16 sharers) co-resident on one XCD's L2 (T1).
// Tile: BM=64, BN=64, BK=64; 4 waves, wave tile 32x32; LDS 2x32KB -> 2
// blocks/CU. Staging: global_load_lds w=16 + XOR chunk swizzle (rule #21).
// Grid: (4, 32, 4) = 512 blocks.
// ---------------------------------------------------------------------------
__global__ __launch_bounds__(256, 2) void gemm_fused_kernel(
    const u16* __restrict__ Khi, const u16* __restrict__ Klo,
    const u16* __restrict__ xhc, const u16* __restrict__ xlc,
    u16* __restrict__ xhn, u16* __restrict__ xln,
    const float* __restrict__ yt, const void* __restrict__ omega,
    const void* __restrict__ gamma, void* __restrict__ outbase, size_t qoff,
    const int* __restrict__ flagp, int grp)
{
  const int flat = blockIdx.x + 4 * blockIdx.y + 128 * blockIdx.z;
  const int swz  = (flat & 7) * 64 + (flat >> 3);      // 512 % 8 == 0: bijective
  const int bx = swz & 3;
  const int by = (swz >> 2) & 31;
  const int bl = swz >> 7;
  const int b  = grp * 4 + bl;
  const int m0 = by * 64;
  const int c0 = bx * 64;

  // per buffer: Ah[64][64]bf16 @0 (8KB), Al @8192, Bh @16384, Bl @24576
  __shared__ char lds[2][32768];

  const int t    = threadIdx.x;
  const int lane = t & 63;
  const int wid  = t >> 6;
  const int wr   = wid >> 1;    // wave row 0..1 (M)
  const int wc   = wid & 1;     // wave col 0..1 (N)

  const u16* Ah = Khi + (size_t)bl * NN * NN;
  const u16* Al = Klo + (size_t)bl * NN * NN;
  const u16* Bh = xhc + (size_t)b * CC * NN;
  const u16* Bl = xlc + (size_t)b * CC * NN;

  // staging geometry: row = tr (+32 per i), in-row chunk = t&7;
  // source chunk = (t&7) ^ (row&7) -> linear LDS dest holds swizzled layout
  const int tr   = t >> 3;                       // 0..31
  const int phys = (t & 7) ^ (tr & 7);
  const size_t aoff = (size_t)(m0 + tr) * NN + phys * 8;
  const size_t boff = (size_t)(c0 + tr) * NN + phys * 8;
  const int dst = wid * 1024;                    // + lane*16 implicit in HW

  f32x4 acc[2][2];
  const f32x4 zero4 = {0.f, 0.f, 0.f, 0.f};
  #pragma unroll
  for (int i = 0; i < 2; i++)
    #pragma unroll
    for (int j = 0; j < 2; j++) acc[i][j] = zero4;

  auto stage = [&](int bufi, int k0) {
    char* base = &lds[bufi][0];
    #pragma unroll
    for (int i = 0; i < 2; i++) {
      gload16(Ah + aoff + (size_t)i * (32 * NN) + k0, base +         i * 4096 + dst);
      gload16(Al + aoff + (size_t)i * (32 * NN) + k0, base +  8192 + i * 4096 + dst);
      gload16(Bh + boff + (size_t)i * (32 * NN) + k0, base + 16384 + i * 4096 + dst);
      gload16(Bl + boff + (size_t)i * (32 * NN) + k0, base + 24576 + i * 4096 + dst);
    }
  };

  const int l15 = lane & 15;
  const int lk  = lane >> 4;     // 0..3

  auto compute = [&](int bufi) {
    const char* base = &lds[bufi][0];
    #pragma unroll
    for (int ks = 0; ks < 2; ks++) {             // two K=32 MFMA steps per tile
      const int cl = ks * 4 + lk;                // logical 16B chunk (k/8)
      bf16x8 fah[2], fal[2], fbh[2], fbl[2];
      #pragma unroll
      for (int fr = 0; fr < 2; fr++) {
        int r   = wr * 32 + fr * 16 + l15;
        int off = r * 128 + ((cl ^ (r & 7)) << 4);
        fah[fr] = *(const bf16x8*)(base + off);
        fal[fr] = *(const bf16x8*)(base + 8192 + off);
      }
      #pragma unroll
      for (int fc = 0; fc < 2; fc++) {
        int r   = wc * 32 + fc * 16 + l15;
        int off = r * 128 + ((cl ^ (r & 7)) << 4);
        fbh[fc] = *(const bf16x8*)(base + 16384 + off);
        fbl[fc] = *(const bf16x8*)(base + 24576 + off);
      }
      #pragma unroll
      for (int fr = 0; fr < 2; fr++)
        #pragma unroll
        for (int fc = 0; fc < 2; fc++) {
          acc[fr][fc] = __builtin_amdgcn_mfma_f32_16x16x32_bf16(
              fah[fr], fbh[fc], acc[fr][fc], 0, 0, 0);
          acc[fr][fc] = __builtin_amdgcn_mfma_f32_16x16x32_bf16(
              fah[fr], fbl[fc], acc[fr][fc], 0, 0, 0);
          acc[fr][fc] = __builtin_amdgcn_mfma_f32_16x16x32_bf16(
              fal[fr], fbh[fc], acc[fr][fc], 0, 0, 0);
        }
    }
  };

  stage(0, 0);
  __syncthreads();
  int buf = 0;
  for (int kt = 0; kt < NN / 64; kt++) {
    if (kt + 1 < NN / 64) stage(buf ^ 1, (kt + 1) * 64);
    compute(buf);
    __syncthreads();
    buf ^= 1;
  }

  // ---- fused Kuramoto step epilogue ----
  // C/D layout: col = c0 + wc*32 + fc*16 + l15; rows rbase..rbase+3.
  // Channel group g = c>>2 spans lanes differing in bits 0..1 (l15&3).
  const bool f32 = (*flagp != 0);
  const float gm = ldin(gamma, 0, f32);
  #pragma unroll
  for (int fr = 0; fr < 2; fr++) {
    const int rbase = m0 + wr * 32 + fr * 16 + lk * 4;
    #pragma unroll
    for (int fc = 0; fc < 2; fc++) {
      const int c = c0 + wc * 32 + fc * 16 + l15;
      const size_t xoff = ((size_t)b * CC + c) * NN + rbase;
      ushort4 xh4 = *(const ushort4*)(xhc + xoff);
      ushort4 xl4 = *(const ushort4*)(xlc + xoff);
      float xcv[4] = { b2f(xh4.x) + b2f(xl4.x), b2f(xh4.y) + b2f(xl4.y),
                       b2f(xh4.z) + b2f(xl4.z), b2f(xh4.w) + b2f(xl4.w) };
      float om   = fabsf(ldin(omega, c >> 1, f32));
      float omsg = (c & 1) ? -om : om;
      float xn[4];
      #pragma unroll
      for (int r = 0; r < 4; r++) {
        const int n = rbase + r;
        float f = acc[fr][fc][r] + yt[((size_t)b * NN + n) * CC + c];
        float s = xcv[r] * f;
        s += __shfl_xor(s, 1);
        s += __shfl_xor(s, 2);
        float xp = __shfl_xor(xcv[r], 1);       // pair partner channel c^1
        float d  = omsg * xp + (f - s * xcv[r]);
        float v  = xcv[r] + gm * d;
        float n2 = v * v;
        n2 += __shfl_xor(n2, 1);
        n2 += __shfl_xor(n2, 2);
        float scl = 1.0f / sqrtf(fmaxf(n2, 1e-6f));
        xn[r] = v * scl;
        const size_t oidx = qoff + ((size_t)b * NN + n) * CC + c;
        if (f32) ((float*)outbase)[oidx] = xn[r];
        else     ((u16*)outbase)[oidx]   = f2b(xn[r]);
      }
      ushort4 nh, nl;
      #pragma unroll
      for (int r = 0; r < 4; r++) {
        u16 h = f2b(xn[r]);
        ((u16*)&nh)[r] = h;
        ((u16*)&nl)[r] = f2b(xn[r] - b2f(h));
      }
      *(ushort4*)(xhn + xoff) = nh;
      *(ushort4*)(xln + xoff) = nl;
    }
  }
}

// ---------------------------------------------------------------------------
extern "C" void kernel_launch(void* const* d_in, const int* in_sizes, int n_in,
                              void* d_out, int out_size, void* d_ws, size_t ws_size,
                              hipStream_t stream) {
  const void* x     = d_in[0];
  const void* y     = d_in[1];
  const void* sc    = d_in[2];
  const void* U     = d_in[3];
  const void* omega = d_in[4];
  const void* gw    = d_in[5];
  const void* gb    = d_in[6];
  const void* gamma = d_in[7];
  // d_in[8] = Q (int32) — fixed at 8 by the problem setup.
  char* ws = (char*)d_ws;

  // Workspace layout (~117.4 MB, under the 125.8 MB previously exercised)
  const size_t BNC = (size_t)BB * NN * CC;               // 4,194,304
  u16*   Khi  = (u16*)(ws);                              // 33,554,432 B
  u16*   Klo  = (u16*)(ws + 33554432);                   // 33,554,432 B
  float* yt   = (float*)(ws + 67108864);                 // 16,777,216 B
  u16*   xAh  = (u16*)(ws + 83886080);                   //  8,388,608 B
  u16*   xAl  = (u16*)(ws + 92274688);                   //  8,388,608 B
  u16*   xBh  = (u16*)(ws + 100663296);                  //  8,388,608 B
  u16*   xBl  = (u16*)(ws + 109051904);                  //  8,388,608 B
  float* murs = (float*)(ws + 117440512);                //  4 KB
  int*   flag = (int*)  (ws + 117444608);                //  4 B

  u16* xh[2] = { xAh, xBh };
  u16* xl[2] = { xAl, xBl };

  detect_kernel<<<dim3(1), dim3(256), 0, stream>>>((const u16*)sc, flag);
  gn_stats_kernel<<<dim3(512), dim3(256), 0, stream>>>(y, murs, flag);
  y_tf_kernel<<<dim3(32, 8), dim3(64, 4), 0, stream>>>(y, murs, gw, gb, yt, flag);
  x_init_kernel<<<dim3(32, 8), dim3(64, 4), 0, stream>>>(x, xAh, xAl, flag);

  for (int grp = 0; grp < 2; grp++) {
    build_k_kernel<<<dim3(64, 64), dim3(32, 8), 0, stream>>>(
        sc, U, Khi, Klo, flag, grp);
    for (int q = 0; q < QQ; q++) {
      const int cur = q & 1, nxt = cur ^ 1;
      gemm_fused_kernel<<<dim3(4, 32, 4), dim3(256), 0, stream>>>(
          Khi, Klo, xh[cur], xl[cur], xh[nxt], xl[nxt],
          yt, omega, gamma, d_out, (size_t)q * BNC, flag, grp);
    }
  }
}